// Round 6
// baseline (1118.939 us; speedup 1.0000x reference)
//
#include <hip/hip_runtime.h>
#include <hip/hip_bf16.h>

#define BB 128
#define LL 128
#define DD 300
#define MDIM 50
#define GINDIM 350
#define HDIM 256     // per-direction hidden
#define G3 768       // 3*HDIM
#define HH 512       // ctx dim
#define RR 128
#define TT 4
#define NKB 4        // branches
#define MTOT (BB*LL) // 16384
#define N2 1536      // both dirs stacked gates
#define KP 352       // padded GRU-input K

typedef __attribute__((ext_vector_type(8))) short short8;
typedef __attribute__((ext_vector_type(4))) float f32x4;

// ---------------- ws layout (bytes) ----------------
#define OFF_GI      0ull            // bf16 [2][16384][768] = 50,331,648
#define OFF_CTXB    50331648ull     // bf16 [16384][512] = 16,777,216
#define OFF_XBF     67108864ull     // bf16 [16384][352] = 11,534,336
#define OFF_WIHB    78643200ull     // bf16 [1536][352]  = 1,081,344
#define OFF_WHHB    79724544ull     // bf16 [2][768][256]= 786,432
#define OFF_BIAS    80510976ull     // f32 [1536]
#define OFF_W2      80517120ull     // f32 [16][512] = 32,768
#define OFF_B2      80549888ull     // f32 [16]
#define OFF_BEG     80550144ull     // int [128]
#define OFF_TN      80550656ull     // int [128]
#define OFF_SCORES  80551168ull     // f32 [128][3]
#define OFF_FK      80553216ull     // f32 [4][16384][4] = 1,048,576
#define OFF_AL      81601792ull     // f32 [4][128][128][4] = 1,048,576
#define OFF_SP      82650368ull     // f32 [4][128][128] = 262,144
#define OFF_SPSUM   82912512ull     // f32 [4][128]
#define OFF_SV      82914560ull     // f32 [128][2048] = 1,048,576

__device__ __forceinline__ float sig_f(float x) { return 1.f / (1.f + __expf(-x)); }
__device__ __forceinline__ float tanh_f(float x) { float e = __expf(2.f * x); return 1.f - 2.f / (e + 1.f); }
__device__ __forceinline__ float b2f(unsigned short u) { return __uint_as_float(((unsigned)u) << 16); }

__device__ __forceinline__ void gload_lds16(const void* g, void* l) {
    __builtin_amdgcn_global_load_lds((const __attribute__((address_space(1))) unsigned int*)g,
                                     (__attribute__((address_space(3))) unsigned int*)l, 16, 0, 0);
}

// ---------------- zero ctxb ----------------
__global__ __launch_bounds__(256) void k_zero(float4* p) {
    size_t n4 = 16777216ull / 16;
    for (size_t i = blockIdx.x * 256ull + threadIdx.x; i < n4; i += (size_t)gridDim.x * 256ull)
        p[i] = make_float4(0.f, 0.f, 0.f, 0.f);
}

// ---------------- prep: x_bf16 [16384][352] ----------------
__global__ __launch_bounds__(256) void k_prep_x(const float* __restrict__ sents,
        const float* __restrict__ mask_table, const int* __restrict__ masks,
        __hip_bfloat16* __restrict__ xbf) {
    int idx = blockIdx.x * 256 + threadIdx.x;
    if (idx >= MTOT * KP) return;
    int m = idx / KP, k = idx % KP;
    float v = 0.f;
    if (k < DD) v = sents[(size_t)m * DD + k];
    else if (k < GINDIM) v = mask_table[masks[m] * MDIM + (k - DD)];
    xbf[idx] = __float2bfloat16(v);
}

// ---------------- prep: WihB bf16 [1536][352] + biasAll (bhr/bhz folded) ----------------
__global__ __launch_bounds__(256) void k_prep_wihB(const float* __restrict__ Wf,
        const float* __restrict__ Wb, const float* __restrict__ bf_,
        const float* __restrict__ bb_, const float* __restrict__ bhf_,
        const float* __restrict__ bhb_, __hip_bfloat16* __restrict__ wihB,
        float* __restrict__ biasAll) {
    int idx = blockIdx.x * 256 + threadIdx.x;
    if (idx < N2 * KP) {
        int n = idx / KP, k = idx % KP;
        int dir = n >= G3; int g = n - dir * G3;
        const float* W = dir ? Wb : Wf;
        float v = (k < GINDIM) ? W[(size_t)g * GINDIM + k] : 0.f;
        wihB[idx] = __float2bfloat16(v);
    }
    if (idx < N2) {
        int dir = idx >= G3; int g = idx - dir * G3;
        float v = dir ? bb_[g] : bf_[g];
        if (g < 2 * HDIM) v += dir ? bhb_[g] : bhf_[g];   // fold r,z hidden bias into gi
        biasAll[idx] = v;
    }
}

// ---------------- prep: WhhB bf16 [2][768][256] ----------------
__global__ __launch_bounds__(256) void k_prep_whhB(const float* __restrict__ Wf,
        const float* __restrict__ Wb, __hip_bfloat16* __restrict__ whhB) {
    int idx = blockIdx.x * 256 + threadIdx.x;
    if (idx >= 2 * G3 * HDIM) return;
    int dir = idx / (G3 * HDIM);
    const float* W = dir ? Wb : Wf;
    whhB[idx] = __float2bfloat16(W[idx - dir * G3 * HDIM]);
}

// ---------------- prep: W2[kt][512] = tW_k[t] @ hW_k ; b2 ----------------
__global__ __launch_bounds__(256) void k_prep_w2(const float* __restrict__ hW,
        const float* __restrict__ hb, const float* __restrict__ tW,
        const float* __restrict__ tb, float* __restrict__ W2, float* __restrict__ b2) {
    int idx = blockIdx.x * 256 + threadIdx.x;   // 16*512
    if (idx < 16 * HH) {
        int kt = idx >> 9, h = idx & 511;
        int k = kt >> 2, t = kt & 3;
        const float* tw = tW + (size_t)(k * TT + t) * RR;
        const float* hw = hW + (size_t)k * RR * HH + h;
        float acc = 0.f;
        #pragma unroll 4
        for (int r = 0; r < RR; ++r) acc += tw[r] * hw[(size_t)r * HH];
        W2[idx] = acc;
    }
    if (idx < 16) {
        int k = idx >> 2, t = idx & 3;
        const float* tw = tW + (size_t)(k * TT + t) * RR;
        const float* hbk = hb + k * RR;
        float acc = tb[k * TT + t];
        for (int r = 0; r < RR; ++r) acc += tw[r] * hbk[r];
        b2[idx] = acc;
    }
}

__global__ __launch_bounds__(128) void k_prep_bt(const int* __restrict__ masks,
        int* __restrict__ beg, int* __restrict__ tn) {
    int b = threadIdx.x;
    int best = masks[b * LL]; int idx = 0; int s = 0;
    for (int j = 0; j < LL; ++j) {
        int v = masks[b * LL + j]; s += v;
        if (v > best) { best = v; idx = j; }
    }
    beg[b] = idx; tn[b] = s;
}

// ---------------- MFMA GEMM 1: gi = x @ Wih^T + bias ----------------
__global__ __launch_bounds__(256) void k_mfma_gi(const short* __restrict__ xbf,
        const short* __restrict__ wihB, const float* __restrict__ biasAll,
        __hip_bfloat16* __restrict__ gi) {
    __shared__ short As[64][40];
    __shared__ short Bs[64][40];
    const int tid = threadIdx.x;
    const int m0 = blockIdx.y * 64, n0 = blockIdx.x * 64;
    const int w = tid >> 6, lane = tid & 63;
    const int srow = tid >> 2, skc = (tid & 3) * 8;
    const int frow = lane & 15, fkc = (lane >> 4) * 8;
    const int rb = (w >> 1) * 32, cb = (w & 1) * 32;
    f32x4 zero = {0.f, 0.f, 0.f, 0.f};
    f32x4 acc[2][2] = {zero, zero, zero, zero};
    for (int k0 = 0; k0 < KP; k0 += 32) {
        *(short8*)&As[srow][skc] = *(const short8*)&xbf[(size_t)(m0 + srow) * KP + k0 + skc];
        *(short8*)&Bs[srow][skc] = *(const short8*)&wihB[(size_t)(n0 + srow) * KP + k0 + skc];
        __syncthreads();
        short8 a[2], b[2];
        #pragma unroll
        for (int i = 0; i < 2; ++i) a[i] = *(const short8*)&As[rb + i * 16 + frow][fkc];
        #pragma unroll
        for (int j = 0; j < 2; ++j) b[j] = *(const short8*)&Bs[cb + j * 16 + frow][fkc];
        #pragma unroll
        for (int i = 0; i < 2; ++i)
            #pragma unroll
            for (int j = 0; j < 2; ++j)
                acc[i][j] = __builtin_amdgcn_mfma_f32_16x16x32_bf16(a[i], b[j], acc[i][j], 0, 0, 0);
        __syncthreads();
    }
    #pragma unroll
    for (int i = 0; i < 2; ++i) {
        #pragma unroll
        for (int j = 0; j < 2; ++j) {
            int col = n0 + cb + j * 16 + frow;
            int dir = col >= G3; int g = col - dir * G3;
            float bias = biasAll[col];
            #pragma unroll
            for (int r = 0; r < 4; ++r) {
                int m = m0 + rb + i * 16 + (lane >> 4) * 4 + r;
                gi[((size_t)dir * MTOT + m) * G3 + g] = __float2bfloat16(acc[i][j][r] + bias);
            }
        }
    }
}

// ---------------- pos weight ----------------
__device__ __forceinline__ float poswt(int j, int beg, int tn, int len, float lf, int mv) {
    float w = (j < beg) ? (1.f - (float)(beg - j) / lf) : 0.f;
    if (mv == 1) w = 1.f;
    if (j > beg + tn) w = 1.f - (float)(j - beg) / lf;
    if (j > len) w = 0.f;
    return w;
}

// ---------------- GRU recurrence via MFMA: 16 blocks (2 dir x 8 groups of 16 batches) ----------------
#define LB(ct,kk) const short8 bu_##ct##_##kk = *(const short8*)(wB + (ct * 16) * HDIM + (kk) * 32);
#define LBCT(ct) LB(ct,0) LB(ct,1) LB(ct,2) LB(ct,3) LB(ct,4) LB(ct,5) LB(ct,6) LB(ct,7)
#define MM(kk) { const short8 a = *(const short8*)(aB + (kk) * 32); \
    acc0 = __builtin_amdgcn_mfma_f32_16x16x32_bf16(a, bu_0_##kk, acc0, 0, 0, 0); \
    acc1 = __builtin_amdgcn_mfma_f32_16x16x32_bf16(a, bu_1_##kk, acc1, 0, 0, 0); \
    acc2 = __builtin_amdgcn_mfma_f32_16x16x32_bf16(a, bu_2_##kk, acc2, 0, 0, 0); \
    acc3 = __builtin_amdgcn_mfma_f32_16x16x32_bf16(a, bu_3_##kk, acc3, 0, 0, 0); \
    acc4 = __builtin_amdgcn_mfma_f32_16x16x32_bf16(a, bu_4_##kk, acc4, 0, 0, 0); \
    acc5 = __builtin_amdgcn_mfma_f32_16x16x32_bf16(a, bu_5_##kk, acc5, 0, 0, 0); }
#define GW(ct) { const int col = colg + ct * 16 + frow; \
    gates[r0 + 0][col] = acc##ct[0]; gates[r0 + 1][col] = acc##ct[1]; \
    gates[r0 + 2][col] = acc##ct[2]; gates[r0 + 3][col] = acc##ct[3]; }
#define NQ(q, hvq) { \
    const int bl = bbase + q; \
    const int len = s_len[bl]; \
    const bool valid = l < len; \
    int pos = dir ? (len - 1 - l) : l; \
    if (!valid) pos = 0; \
    const short* gb = &giLds[(l & 1) * 12288 + bl * 768]; \
    float gvr = b2f((unsigned short)gb[i_idx]); \
    float gvz = b2f((unsigned short)gb[256 + i_idx]); \
    float gvn = b2f((unsigned short)gb[512 + i_idx]); \
    float rr = sig_f(gvr + gates[bl][i_idx]); \
    float zz = sig_f(gvz + gates[bl][HDIM + i_idx]); \
    float nn = tanh_f(gvn + rr * (gates[bl][2 * HDIM + i_idx] + bhn)); \
    float h = (1.f - zz) * nn + zz * hvq; \
    if (valid) { \
        hvq = h; \
        __hip_bfloat16 hb16 = __float2bfloat16(h); \
        hA[bl][i_idx] = *(short*)&hb16; \
        float hw = h * s_w[bl][pos]; \
        ctxb[((size_t)(b0 + bl) * LL + pos) * HH + dirH + i_idx] = __float2bfloat16(hw); \
    } }

__global__ __launch_bounds__(512) __attribute__((amdgpu_waves_per_eu(2, 2)))
void k_gru_mfma(
        const short* __restrict__ gi, const short* __restrict__ whhB,
        const float* __restrict__ gbhhf, const float* __restrict__ gbhhb,
        const int* __restrict__ lens, const int* __restrict__ masks,
        const int* __restrict__ beg_, const int* __restrict__ tn_,
        __hip_bfloat16* __restrict__ ctxb) {
    __shared__ float gates[16][772];     // 49,408 B
    __shared__ short hA[16][264];        //  8,448 B
    __shared__ float s_w[16][128];       //  8,192 B
    __shared__ short giLds[2 * 12288];   // 49,152 B (double-buffered gi rows)
    __shared__ int s_len[16];
    __shared__ int s_maxlen;

    const int tid = threadIdx.x;
    const int w = tid >> 6, lane = tid & 63;
    const int dir = blockIdx.x >> 3, grp = blockIdx.x & 7;
    const int b0 = grp * 16;
    const int frow = lane & 15, fkc = (lane >> 4) * 8;
    const int colg = w * 96;
    const int r0 = (lane >> 4) * 4;
    const int dirH = dir * HDIM;

    if (tid < 16) s_len[tid] = lens[b0 + tid];
    for (int e = tid; e < 16 * 264; e += 512) ((short*)hA)[e] = 0;
    __syncthreads();
    if (tid == 0) {
        int m = 0;
        #pragma unroll
        for (int q = 0; q < 16; ++q) m = max(m, s_len[q]);
        s_maxlen = m;
    }
    for (int e = tid; e < 16 * 128; e += 512) {
        int bl = e >> 7, j = e & 127;
        int b = b0 + bl;
        int len = s_len[bl];
        s_w[bl][j] = poswt(j, beg_[b], tn_[b], len, (float)len, masks[b * LL + j]);
    }

    // ---- B fragments: 48 named short8 (192 VGPR), fully static ----
    const short* wB = whhB + ((size_t)dir * G3 + colg + frow) * HDIM + fkc;
    LBCT(0) LBCT(1) LBCT(2) LBCT(3) LBCT(4) LBCT(5)

    const int i_idx = tid & 255;
    const int bbase = (tid >> 8) * 8;
    const float bhn = (dir ? gbhhb : gbhhf)[2 * HDIM + i_idx];
    const short* giD = gi + (size_t)dir * MTOT * G3;
    const short* aB = &hA[frow][fkc];
    float hv0 = 0.f, hv1 = 0.f, hv2 = 0.f, hv3 = 0.f, hv4 = 0.f, hv5 = 0.f, hv6 = 0.f, hv7 = 0.f;
    __syncthreads();
    const int maxlen = s_maxlen;

    // stage gi rows for step ll into LDS buffer bsel (async, zero VGPR residency)
    auto stage = [&](int ll, int bsel) {
        #pragma unroll
        for (int j = 0; j < 3; ++j) {
            int flat = j * 512 + tid;              // 16B-chunk id, 0..1535
            int bl = flat / 96;
            int off16 = flat - bl * 96;
            int len = s_len[bl];
            int pos = dir ? (len - 1 - ll) : ll;
            if (ll >= len) pos = 0;
            const char* src = (const char*)giD + ((size_t)((b0 + bl) * LL + pos) * G3 + off16 * 8) * 2;
            short* dst = &giLds[bsel * 12288 + (j * 512 + (tid & ~63)) * 8];
            gload_lds16(src, dst);
        }
    };
    stage(0, 0);

    const f32x4 zero = {0.f, 0.f, 0.f, 0.f};
    for (int l = 0; l < maxlen; ++l) {
        if (l + 1 < maxlen) stage(l + 1, (l + 1) & 1);
        // ---- MFMA: gates_pre = h @ Whh^T (fully static unrolled) ----
        f32x4 acc0 = zero, acc1 = zero, acc2 = zero, acc3 = zero, acc4 = zero, acc5 = zero;
        MM(0) MM(1) MM(2) MM(3) MM(4) MM(5) MM(6) MM(7)
        GW(0) GW(1) GW(2) GW(3) GW(4) GW(5)
        __syncthreads();   // gates visible; staged gi drained
        // ---- nonlinearity (gi from LDS) ----
        NQ(0, hv0) NQ(1, hv1) NQ(2, hv2) NQ(3, hv3)
        NQ(4, hv4) NQ(5, hv5) NQ(6, hv6) NQ(7, hv7)
        __syncthreads();   // hA update visible before next MFMA
    }
}

// ---------------- fused fk = ctxb @ W2^T + b2 ----------------
__global__ __launch_bounds__(256) void k_fk(const __hip_bfloat16* __restrict__ ctxb,
        const float* __restrict__ W2, const float* __restrict__ b2,
        float* __restrict__ fk) {
    int gid = blockIdx.x * 256 + threadIdx.x;  // MTOT*16
    int m = gid >> 4, kt = gid & 15;
    const short8* crow = (const short8*)((const short*)ctxb + (size_t)m * HH);
    const float* w2 = W2 + kt * HH;
    float acc = b2[kt];
    #pragma unroll 4
    for (int c = 0; c < HH / 8; ++c) {
        short8 v = crow[c];
        #pragma unroll
        for (int j = 0; j < 8; ++j)
            acc += b2f((unsigned short)v[j]) * w2[c * 8 + j];
    }
    fk[((size_t)(kt >> 2) * MTOT + m) * TT + (kt & 3)] = acc;
}

// ---------------- CRF forward/backward marginals (4 lanes per (k,b)) ----------------
__global__ __launch_bounds__(64) void k_crf(const float* __restrict__ fk,
        const float* __restrict__ trans, const int* __restrict__ lens,
        float* __restrict__ alphas, float* __restrict__ sp, float* __restrict__ spsum) {
    const int tid = blockIdx.x * 64 + threadIdx.x;   // 2048 total
    const int pid = tid >> 2;                        // 512 pairs
    const int t = tid & 3;
    const int k = pid >> 7, b = pid & 127;
    const int len = lens[b];
    const float* f = fk + ((size_t)k * MTOT + (size_t)b * LL) * TT;
    const float* tr = trans + k * 16;
    const float trC0 = tr[0 * 4 + t], trC1 = tr[1 * 4 + t], trC2 = tr[2 * 4 + t], trC3 = tr[3 * 4 + t];
    const float trR0 = tr[t * 4 + 0], trR1 = tr[t * 4 + 1], trR2 = tr[t * 4 + 2], trR3 = tr[t * 4 + 3];
    float* al = alphas + ((size_t)k * BB + b) * LL * TT;
    const int base = threadIdx.x & ~3;
    float alpha = f[t];
    al[t] = alpha;
    for (int l = 1; l < LL; ++l) {
        float a0 = __shfl(alpha, base + 0);
        float a1 = __shfl(alpha, base + 1);
        float a2 = __shfl(alpha, base + 2);
        float a3 = __shfl(alpha, base + 3);
        float v0 = a0 + trC0, v1 = a1 + trC1, v2 = a2 + trC2, v3 = a3 + trC3;
        float mx = fmaxf(fmaxf(v0, v1), fmaxf(v2, v3));
        float sum = __expf(v0 - mx) + __expf(v1 - mx) + __expf(v2 - mx) + __expf(v3 - mx);
        float nw = mx + __logf(sum) + f[l * TT + t];
        if (l < len) alpha = nw;
        al[l * TT + t] = alpha;
    }
    float beta = 0.f;
    float ssum = 0.f;
    for (int l = LL - 1; l >= 0; --l) {
        if (l < LL - 1) {
            float fb = f[(l + 1) * TT + t] + beta;
            float c0 = __shfl(fb, base + 0);
            float c1 = __shfl(fb, base + 1);
            float c2 = __shfl(fb, base + 2);
            float c3 = __shfl(fb, base + 3);
            float w0 = trR0 + c0, w1 = trR1 + c1, w2 = trR2 + c2, w3 = trR3 + c3;
            float mx = fmaxf(fmaxf(w0, w1), fmaxf(w2, w3));
            float nb = mx + __logf(__expf(w0 - mx) + __expf(w1 - mx) + __expf(w2 - mx) + __expf(w3 - mx));
            if (l + 1 < len) beta = nb;
        }
        float v = al[l * TT + t] + beta;
        float mx = fmaxf(v, __shfl_xor(v, 1));
        mx = fmaxf(mx, __shfl_xor(mx, 2));
        float p = __expf(v - mx);
        float s = p;
        s += __shfl_xor(s, 1);
        s += __shfl_xor(s, 2);
        float m1 = __shfl(p, base + 1) / s;
        float spv = (l < len) ? m1 : 0.f;
        if (t == 0) sp[((size_t)k * BB + b) * LL + l] = spv;
        ssum += spv;
    }
    if (t == 0) spsum[k * BB + b] = ssum;
}

// ---------------- pooling: sv[b, k*512+h] (bf16 ctx, vectorized) ----------------
__global__ __launch_bounds__(256) void k_pool(const __hip_bfloat16* __restrict__ ctxb,
        const float* __restrict__ sp, const float* __restrict__ spsum,
        float* __restrict__ sv) {
    __shared__ float s_sp[NKB][LL];
    __shared__ float s_inv[NKB];
    const int b = blockIdx.x;
    const int tid = threadIdx.x;
    for (int i = tid; i < NKB * LL; i += 256) {
        int k = i >> 7, l = i & 127;
        s_sp[k][l] = sp[((size_t)k * BB + b) * LL + l];
    }
    if (tid < NKB) s_inv[tid] = 1.f / spsum[tid * BB + b];
    __syncthreads();
    const int n0 = tid * 8;
    const int k = n0 >> 9, h0 = n0 & 511;
    float acc[8] = {};
    const short* cb = (const short*)ctxb;
    for (int l = 0; l < LL; ++l) {
        float spl = s_sp[k][l];
        short8 v = *(const short8*)&cb[((size_t)b * LL + l) * HH + h0];
        #pragma unroll
        for (int j = 0; j < 8; ++j)
            acc[j] += spl * b2f((unsigned short)v[j]);
    }
    float inv = s_inv[k];
    #pragma unroll
    for (int j = 0; j < 8; ++j)
        sv[(size_t)b * 2048 + n0 + j] = acc[j] * inv;
}

// ---------------- scores[b][3] = relu(sv[b]) @ lW^T + lb ----------------
__global__ __launch_bounds__(256) void k_scores(const float* __restrict__ sv,
        const float* __restrict__ lW, const float* __restrict__ lb,
        float* __restrict__ scores) {
    __shared__ float red[3][4];
    const int b = blockIdx.x;
    const int tid = threadIdx.x;
    const float* svb = sv + (size_t)b * 2048;
    float a0 = 0.f, a1 = 0.f, a2 = 0.f;
    for (int i = tid; i < 2048; i += 256) {
        float v = fmaxf(svb[i], 0.f);
        a0 += v * lW[i];
        a1 += v * lW[2048 + i];
        a2 += v * lW[4096 + i];
    }
    #pragma unroll
    for (int off = 32; off > 0; off >>= 1) {
        a0 += __shfl_down(a0, off);
        a1 += __shfl_down(a1, off);
        a2 += __shfl_down(a2, off);
    }
    const int wid = tid >> 6, lane = tid & 63;
    if (lane == 0) { red[0][wid] = a0; red[1][wid] = a1; red[2][wid] = a2; }
    __syncthreads();
    if (tid < 3) {
        scores[b * 3 + tid] = red[tid][0] + red[tid][1] + red[tid][2] + red[tid][3] + lb[tid];
    }
}

// ---------------- final: log-softmax + mean NLL (float32 out) ----------------
__global__ __launch_bounds__(128) void k_final2(const float* __restrict__ scores,
        const int* __restrict__ labels, float* __restrict__ out) {
    __shared__ float red[128];
    const int b = threadIdx.x;
    float s0 = scores[b * 3 + 0], s1 = scores[b * 3 + 1], s2 = scores[b * 3 + 2];
    float mx = fmaxf(s0, fmaxf(s1, s2));
    float lse = mx + logf(expf(s0 - mx) + expf(s1 - mx) + expf(s2 - mx));
    int lab = labels[b];
    float sc = lab == 0 ? s0 : (lab == 1 ? s1 : s2);
    red[b] = lse - sc;
    __syncthreads();
    for (int st = 64; st > 0; st >>= 1) {
        if (b < st) red[b] += red[b + st];
        __syncthreads();
    }
    if (b == 0) out[0] = red[0] * (1.f / 128.f);
}

extern "C" void kernel_launch(void* const* d_in, const int* in_sizes, int n_in,
                              void* d_out, int out_size, void* d_ws, size_t ws_size,
                              hipStream_t stream) {
    const float* sents      = (const float*)d_in[0];
    const float* mask_table = (const float*)d_in[1];
    const float* gWihf      = (const float*)d_in[2];
    const float* gWhhf      = (const float*)d_in[3];
    const float* gbihf      = (const float*)d_in[4];
    const float* gbhhf      = (const float*)d_in[5];
    const float* gWihb      = (const float*)d_in[6];
    const float* gWhhb      = (const float*)d_in[7];
    const float* gbihb      = (const float*)d_in[8];
    const float* gbhhb      = (const float*)d_in[9];
    const float* hW         = (const float*)d_in[10];
    const float* hb         = (const float*)d_in[11];
    const float* tW         = (const float*)d_in[12];
    const float* tb         = (const float*)d_in[13];
    const float* trans      = (const float*)d_in[14];
    const float* lW         = (const float*)d_in[15];
    const float* lb         = (const float*)d_in[16];
    const int*   masks      = (const int*)d_in[17];
    const int*   lens       = (const int*)d_in[18];
    const int*   labels     = (const int*)d_in[19];

    char* wsb = (char*)d_ws;
    __hip_bfloat16* gi    = (__hip_bfloat16*)(wsb + OFF_GI);
    __hip_bfloat16* ctxb  = (__hip_bfloat16*)(wsb + OFF_CTXB);
    __hip_bfloat16* xbf   = (__hip_bfloat16*)(wsb + OFF_XBF);
    __hip_bfloat16* wihB  = (__hip_bfloat16*)(wsb + OFF_WIHB);
    __hip_bfloat16* whhB  = (__hip_bfloat16*)(wsb + OFF_WHHB);
    float* biasAll        = (float*)(wsb + OFF_BIAS);
    float* W2             = (float*)(wsb + OFF_W2);
    float* b2             = (float*)(wsb + OFF_B2);
    int* beg              = (int*)(wsb + OFF_BEG);
    int* tn               = (int*)(wsb + OFF_TN);
    float* scores         = (float*)(wsb + OFF_SCORES);
    float* fk             = (float*)(wsb + OFF_FK);
    float* alphas         = (float*)(wsb + OFF_AL);
    float* sp             = (float*)(wsb + OFF_SP);
    float* spsum          = (float*)(wsb + OFF_SPSUM);
    float* sv             = (float*)(wsb + OFF_SV);

    hipLaunchKernelGGL(k_zero, dim3(1024), dim3(256), 0, stream, (float4*)(wsb + OFF_CTXB));
    hipLaunchKernelGGL(k_prep_x, dim3((MTOT * KP + 255) / 256), dim3(256), 0, stream,
                       sents, mask_table, masks, xbf);
    hipLaunchKernelGGL(k_prep_wihB, dim3((N2 * KP + 255) / 256), dim3(256), 0, stream,
                       gWihf, gWihb, gbihf, gbihb, gbhhf, gbhhb, wihB, biasAll);
    hipLaunchKernelGGL(k_prep_whhB, dim3((2 * G3 * HDIM + 255) / 256), dim3(256), 0, stream,
                       gWhhf, gWhhb, whhB);
    hipLaunchKernelGGL(k_prep_w2, dim3((16 * HH + 255) / 256), dim3(256), 0, stream,
                       hW, hb, tW, tb, W2, b2);
    hipLaunchKernelGGL(k_prep_bt, dim3(1), dim3(128), 0, stream, masks, beg, tn);

    hipLaunchKernelGGL(k_mfma_gi, dim3(N2 / 64, MTOT / 64), dim3(256), 0, stream,
                       (const short*)xbf, (const short*)wihB, biasAll, gi);
    hipLaunchKernelGGL(k_gru_mfma, dim3(16), dim3(512), 0, stream,
                       (const short*)gi, (const short*)whhB, gbhhf, gbhhb, lens, masks, beg, tn, ctxb);
    hipLaunchKernelGGL(k_fk, dim3(MTOT * 16 / 256), dim3(256), 0, stream,
                       ctxb, W2, b2, fk);
    hipLaunchKernelGGL(k_crf, dim3(32), dim3(64), 0, stream, fk, trans, lens, alphas, sp, spsum);
    hipLaunchKernelGGL(k_pool, dim3(BB), dim3(256), 0, stream, ctxb, sp, spsum, sv);
    hipLaunchKernelGGL(k_scores, dim3(BB), dim3(256), 0, stream, sv, lW, lb, scores);
    hipLaunchKernelGGL(k_final2, dim3(1), dim3(128), 0, stream, scores, labels, (float*)d_out);
}